// Round 12
// baseline (197.577 us; speedup 1.0000x reference)
//
#include <hip/hip_runtime.h>

#define SCAN_CHUNK 1024
#define NPB 32

typedef unsigned int   uint32;
typedef unsigned short ushort16;
typedef __attribute__((ext_vector_type(8))) short bf16x8;
typedef __attribute__((ext_vector_type(4))) float f32x4;
#define MFMA16(a,b,c) __builtin_amdgcn_mfma_f32_16x16x32_bf16(a,b,c,0,0,0)

// bf16 helpers (RNE)
__device__ inline uint32 pack_bf16x2(float a, float b) {
    uint32 ua = __float_as_uint(a);
    uint32 ub = __float_as_uint(b);
    ua += 0x7FFFu + ((ua >> 16) & 1u);
    ub += 0x7FFFu + ((ub >> 16) & 1u);
    return (ua >> 16) | (ub & 0xFFFF0000u);
}
__device__ inline ushort16 bf16_1(float a) {
    uint32 u = __float_as_uint(a);
    u += 0x7FFFu + ((u >> 16) & 1u);
    return (ushort16)(u >> 16);
}
__device__ inline float bf_lo(uint32 u) { return __uint_as_float(u << 16); }
__device__ inline float bf_hi(uint32 u) { return __uint_as_float(u & 0xFFFF0000u); }

// ---------------------------------------------------------------------------
// Zero an int buffer (replaces slow runtime fillBuffer for small sizes)
// ---------------------------------------------------------------------------
__global__ void zero_kernel(int4* __restrict__ p, int n4)
{
    int i = blockIdx.x * blockDim.x + threadIdx.x;
    if (i < n4) p[i] = make_int4(0, 0, 0, 0);
}

// ---------------------------------------------------------------------------
// x fp32 -> bf16
// ---------------------------------------------------------------------------
__global__ void cvt_x_kernel(const float4* __restrict__ xin,
                             uint2* __restrict__ xb, int n4)
{
    int i = blockIdx.x * blockDim.x + threadIdx.x;
    if (i < n4) {
        float4 v = xin[i];
        uint2 o;
        o.x = pack_bf16x2(v.x, v.y);
        o.y = pack_bf16x2(v.z, v.w);
        xb[i] = o;
    }
}

// ---------------------------------------------------------------------------
// CSR build: 8 edges/thread for memory-level parallelism
// ---------------------------------------------------------------------------
__global__ void hist_kernel(const int* __restrict__ dst, int* __restrict__ deg, int E)
{
    int g = blockIdx.x * blockDim.x + threadIdx.x;
    int e0 = g * 8;
    if (e0 + 8 <= E) {
        int4 da = *(const int4*)&dst[e0];
        int4 db = *(const int4*)&dst[e0 + 4];
        atomicAdd(&deg[da.x], 1);
        atomicAdd(&deg[da.y], 1);
        atomicAdd(&deg[da.z], 1);
        atomicAdd(&deg[da.w], 1);
        atomicAdd(&deg[db.x], 1);
        atomicAdd(&deg[db.y], 1);
        atomicAdd(&deg[db.z], 1);
        atomicAdd(&deg[db.w], 1);
    } else {
        for (int e = e0; e < E; e++) atomicAdd(&deg[dst[e]], 1);
    }
}

__global__ __launch_bounds__(256) void scanA_kernel(const int* __restrict__ deg,
                                                    int* __restrict__ part, int N)
{
    __shared__ int red[256];
    int b = blockIdx.x, t = threadIdx.x;
    int base = b * SCAN_CHUNK;
    int s = 0;
    for (int i = t; i < SCAN_CHUNK; i += 256) {
        int idx = base + i;
        s += (idx < N) ? deg[idx] : 0;
    }
    red[t] = s;
    __syncthreads();
    for (int o = 128; o > 0; o >>= 1) {
        if (t < o) red[t] += red[t + o];
        __syncthreads();
    }
    if (t == 0) part[b] = red[0];
}

__global__ void scanB_kernel(int* __restrict__ part, int* __restrict__ offN, int NCH)
{
    int lane = threadIdx.x;
    int orig = (lane < NCH) ? part[lane] : 0;
    int v = orig;
    for (int s = 1; s < 64; s <<= 1) {
        int t = __shfl_up(v, s);
        if (lane >= s) v += t;
    }
    if (lane < NCH) part[lane] = v - orig;
    if (lane == NCH - 1) *offN = v;
}

__global__ __launch_bounds__(SCAN_CHUNK) void scanC_kernel(const int* __restrict__ deg,
                                                           const int* __restrict__ part,
                                                           int* __restrict__ off,
                                                           int* __restrict__ cursor, int N)
{
    __shared__ int buf[SCAN_CHUNK];
    int b = blockIdx.x, t = threadIdx.x;
    int idx = b * SCAN_CHUNK + t;
    int v = (idx < N) ? deg[idx] : 0;
    buf[t] = v;
    __syncthreads();
    for (int s = 1; s < SCAN_CHUNK; s <<= 1) {
        int tmp = (t >= s) ? buf[t - s] : 0;
        __syncthreads();
        buf[t] += tmp;
        __syncthreads();
    }
    int excl = buf[t] - v + part[b];
    if (idx < N) { off[idx] = excl; cursor[idx] = excl; }
}

// 8 edges/thread: 2x int4 coalesced loads, 8 independent atomics, 8 stores
__global__ void fill_kernel(const int* __restrict__ src, const int* __restrict__ dst,
                            int* __restrict__ cursor, int2* __restrict__ elist, int E)
{
    int g = blockIdx.x * blockDim.x + threadIdx.x;
    int e0 = g * 8;
    if (e0 + 8 <= E) {
        int4 sa = *(const int4*)&src[e0];
        int4 sb = *(const int4*)&src[e0 + 4];
        int4 da = *(const int4*)&dst[e0];
        int4 db = *(const int4*)&dst[e0 + 4];
        int p0 = atomicAdd(&cursor[da.x], 1);
        int p1 = atomicAdd(&cursor[da.y], 1);
        int p2 = atomicAdd(&cursor[da.z], 1);
        int p3 = atomicAdd(&cursor[da.w], 1);
        int p4 = atomicAdd(&cursor[db.x], 1);
        int p5 = atomicAdd(&cursor[db.y], 1);
        int p6 = atomicAdd(&cursor[db.z], 1);
        int p7 = atomicAdd(&cursor[db.w], 1);
        elist[p0] = make_int2(sa.x, e0 + 0);
        elist[p1] = make_int2(sa.y, e0 + 1);
        elist[p2] = make_int2(sa.z, e0 + 2);
        elist[p3] = make_int2(sa.w, e0 + 3);
        elist[p4] = make_int2(sb.x, e0 + 4);
        elist[p5] = make_int2(sb.y, e0 + 5);
        elist[p6] = make_int2(sb.z, e0 + 6);
        elist[p7] = make_int2(sb.w, e0 + 7);
    } else {
        for (int e = e0; e < E; e++) {
            int p = atomicAdd(&cursor[dst[e]], 1);
            elist[p] = make_int2(src[e], e);
        }
    }
}

// ---------------------------------------------------------------------------
// Weight composition (layer 1) -> transposed bf16 Wc1T[128][160]
// ---------------------------------------------------------------------------
__global__ __launch_bounds__(128) void compose1_kernel(
    const float* __restrict__ Wmsg1, const float* __restrict__ bmsg1,
    const float* __restrict__ Wapp1, const float* __restrict__ bapp1,
    ushort16* __restrict__ Wc1T, float* __restrict__ b1eff, float* __restrict__ bmW1)
{
    int b = blockIdx.x;   // k-row 0..160
    int j = threadIdx.x;  // 0..127
    if (b < 64) {
        Wc1T[(size_t)j * 160 + b] = bf16_1(Wapp1[b * 128 + j]);
    } else if (b < 160) {
        int ar = b - 64;
        float s = 0.f;
        for (int k = 0; k < 128; k++)
            s = fmaf(Wmsg1[ar * 128 + k], Wapp1[(64 + k) * 128 + j], s);
        Wc1T[(size_t)j * 160 + b] = bf16_1(s);
    } else {
        float s = 0.f;
        for (int k = 0; k < 128; k++)
            s = fmaf(bmsg1[k], Wapp1[(64 + k) * 128 + j], s);
        bmW1[j] = s;
        b1eff[j] = bapp1[j] + s;
    }
}

// ---------------------------------------------------------------------------
// Weight composition (layer 2) -> transposed bf16 Wc2T[64][224]
// ---------------------------------------------------------------------------
__global__ __launch_bounds__(64) void compose2_kernel(
    const float* __restrict__ Wmsg2, const float* __restrict__ bmsg2,
    const float* __restrict__ Wapp2, const float* __restrict__ bapp2,
    ushort16* __restrict__ Wc2T, float* __restrict__ b2eff, float* __restrict__ bmW2)
{
    int b = blockIdx.x;  // 0..224
    int j = threadIdx.x; // 0..63
    if (b < 192) {
        Wc2T[(size_t)j * 224 + b] = bf16_1(Wapp2[b * 64 + j]);
    } else if (b < 224) {
        int ar = 128 + (b - 192);
        float s = 0.f;
        for (int k = 0; k < 64; k++)
            s = fmaf(Wmsg2[ar * 64 + k], Wapp2[(128 + k) * 64 + j], s);
        Wc2T[(size_t)j * 224 + b] = bf16_1(s);
    } else {
        float s = 0.f;
        for (int k = 0; k < 64; k++)
            s = fmaf(bmsg2[k], Wapp2[(128 + k) * 64 + j], s);
        bmW2[j] = s;
        b2eff[j] = bapp2[j] + s;
    }
}

// Wm2hT[64][128] bf16 = transpose of Wmsg2 rows 0..127
__global__ __launch_bounds__(64) void composem_kernel(
    const float* __restrict__ Wmsg2, ushort16* __restrict__ Wm2hT)
{
    int k = blockIdx.x;   // 0..127
    int c = threadIdx.x;  // 0..63
    Wm2hT[(size_t)c * 128 + k] = bf16_1(Wmsg2[k * 64 + c]);
}

// ---------------------------------------------------------------------------
// Layer-1 aggregate: 8 nodes/wave, 8-lane group per node, 4-way unrolled
// ---------------------------------------------------------------------------
__global__ __launch_bounds__(256) void agg1_kernel(const uint4* __restrict__ xb,
                                                   const float4* __restrict__ ea4,
                                                   const int2* __restrict__ elist,
                                                   const int* __restrict__ off,
                                                   float4* __restrict__ A1x,
                                                   float4* __restrict__ A1e, int N)
{
    int tid = blockIdx.x * blockDim.x + threadIdx.x;
    int node = tid >> 3;          // 8 lanes per node
    int s8 = tid & 7;
    if (node >= N) return;
    int beg = off[node], end = off[node + 1];
    float inv = 1.0f / fmaxf((float)(end - beg), 1.0f);

    float ax[8];
#pragma unroll
    for (int q = 0; q < 8; q++) ax[q] = 0.f;
    float4 ae = make_float4(0.f, 0.f, 0.f, 0.f);

    int i = beg;
    for (; i + 4 <= end; i += 4) {
        int2 p0 = elist[i + 0];
        int2 p1 = elist[i + 1];
        int2 p2 = elist[i + 2];
        int2 p3 = elist[i + 3];
        uint4 vx0 = xb[(size_t)p0.x * 8 + s8];
        uint4 vx1 = xb[(size_t)p1.x * 8 + s8];
        uint4 vx2 = xb[(size_t)p2.x * 8 + s8];
        uint4 vx3 = xb[(size_t)p3.x * 8 + s8];
        float4 ve0 = ea4[(size_t)p0.y * 8 + s8];
        float4 ve1 = ea4[(size_t)p1.y * 8 + s8];
        float4 ve2 = ea4[(size_t)p2.y * 8 + s8];
        float4 ve3 = ea4[(size_t)p3.y * 8 + s8];
        ax[0] += (bf_lo(vx0.x) + bf_lo(vx1.x)) + (bf_lo(vx2.x) + bf_lo(vx3.x));
        ax[1] += (bf_hi(vx0.x) + bf_hi(vx1.x)) + (bf_hi(vx2.x) + bf_hi(vx3.x));
        ax[2] += (bf_lo(vx0.y) + bf_lo(vx1.y)) + (bf_lo(vx2.y) + bf_lo(vx3.y));
        ax[3] += (bf_hi(vx0.y) + bf_hi(vx1.y)) + (bf_hi(vx2.y) + bf_hi(vx3.y));
        ax[4] += (bf_lo(vx0.z) + bf_lo(vx1.z)) + (bf_lo(vx2.z) + bf_lo(vx3.z));
        ax[5] += (bf_hi(vx0.z) + bf_hi(vx1.z)) + (bf_hi(vx2.z) + bf_hi(vx3.z));
        ax[6] += (bf_lo(vx0.w) + bf_lo(vx1.w)) + (bf_lo(vx2.w) + bf_lo(vx3.w));
        ax[7] += (bf_hi(vx0.w) + bf_hi(vx1.w)) + (bf_hi(vx2.w) + bf_hi(vx3.w));
        ae.x += (ve0.x + ve1.x) + (ve2.x + ve3.x);
        ae.y += (ve0.y + ve1.y) + (ve2.y + ve3.y);
        ae.z += (ve0.z + ve1.z) + (ve2.z + ve3.z);
        ae.w += (ve0.w + ve1.w) + (ve2.w + ve3.w);
    }
    for (; i < end; i++) {
        int2 pr = elist[i];
        uint4 vx = xb[(size_t)pr.x * 8 + s8];
        float4 ve = ea4[(size_t)pr.y * 8 + s8];
        ax[0] += bf_lo(vx.x); ax[1] += bf_hi(vx.x);
        ax[2] += bf_lo(vx.y); ax[3] += bf_hi(vx.y);
        ax[4] += bf_lo(vx.z); ax[5] += bf_hi(vx.z);
        ax[6] += bf_lo(vx.w); ax[7] += bf_hi(vx.w);
        ae.x += ve.x; ae.y += ve.y; ae.z += ve.z; ae.w += ve.w;
    }
    float4 o0 = make_float4(ax[0] * inv, ax[1] * inv, ax[2] * inv, ax[3] * inv);
    float4 o1 = make_float4(ax[4] * inv, ax[5] * inv, ax[6] * inv, ax[7] * inv);
    A1x[(size_t)node * 16 + s8 * 2 + 0] = o0;
    A1x[(size_t)node * 16 + s8 * 2 + 1] = o1;
    ae.x *= inv; ae.y *= inv; ae.z *= inv; ae.w *= inv;
    A1e[(size_t)node * 8 + s8] = ae;
}

// ---------------------------------------------------------------------------
// Layer-2 aggregate: same structure, 4-way unrolled.
// ---------------------------------------------------------------------------
__global__ __launch_bounds__(256) void agg2_kernel(const uint4* __restrict__ g2b,
                                                   const int2* __restrict__ elist,
                                                   const int* __restrict__ off,
                                                   float4* __restrict__ A2g, int N)
{
    int tid = blockIdx.x * blockDim.x + threadIdx.x;
    int node = tid >> 3;
    int s8 = tid & 7;
    if (node >= N) return;
    int beg = off[node], end = off[node + 1];
    float inv = 1.0f / fmaxf((float)(end - beg), 1.0f);

    float ag[8];
#pragma unroll
    for (int q = 0; q < 8; q++) ag[q] = 0.f;

    int i = beg;
    for (; i + 4 <= end; i += 4) {
        int r0 = elist[i + 0].x;
        int r1 = elist[i + 1].x;
        int r2 = elist[i + 2].x;
        int r3 = elist[i + 3].x;
        uint4 v0 = g2b[(size_t)r0 * 8 + s8];
        uint4 v1 = g2b[(size_t)r1 * 8 + s8];
        uint4 v2 = g2b[(size_t)r2 * 8 + s8];
        uint4 v3 = g2b[(size_t)r3 * 8 + s8];
        ag[0] += (bf_lo(v0.x) + bf_lo(v1.x)) + (bf_lo(v2.x) + bf_lo(v3.x));
        ag[1] += (bf_hi(v0.x) + bf_hi(v1.x)) + (bf_hi(v2.x) + bf_hi(v3.x));
        ag[2] += (bf_lo(v0.y) + bf_lo(v1.y)) + (bf_lo(v2.y) + bf_lo(v3.y));
        ag[3] += (bf_hi(v0.y) + bf_hi(v1.y)) + (bf_hi(v2.y) + bf_hi(v3.y));
        ag[4] += (bf_lo(v0.z) + bf_lo(v1.z)) + (bf_lo(v2.z) + bf_lo(v3.z));
        ag[5] += (bf_hi(v0.z) + bf_hi(v1.z)) + (bf_hi(v2.z) + bf_hi(v3.z));
        ag[6] += (bf_lo(v0.w) + bf_lo(v1.w)) + (bf_lo(v2.w) + bf_lo(v3.w));
        ag[7] += (bf_hi(v0.w) + bf_hi(v1.w)) + (bf_hi(v2.w) + bf_hi(v3.w));
    }
    for (; i < end; i++) {
        int row = elist[i].x;
        uint4 v = g2b[(size_t)row * 8 + s8];
        ag[0] += bf_lo(v.x); ag[1] += bf_hi(v.x);
        ag[2] += bf_lo(v.y); ag[3] += bf_hi(v.y);
        ag[4] += bf_lo(v.z); ag[5] += bf_hi(v.z);
        ag[6] += bf_lo(v.w); ag[7] += bf_hi(v.w);
    }
    float4 o0 = make_float4(ag[0] * inv, ag[1] * inv, ag[2] * inv, ag[3] * inv);
    float4 o1 = make_float4(ag[4] * inv, ag[5] * inv, ag[6] * inv, ag[7] * inv);
    A2g[(size_t)node * 16 + s8 * 2 + 0] = o0;
    A2g[(size_t)node * 16 + s8 * 2 + 1] = o1;
}

// ---------------------------------------------------------------------------
// Layer-1 node kernel (MFMA) — unchanged
// ---------------------------------------------------------------------------
__global__ __launch_bounds__(512) void node1_kernel(
    const uint32* __restrict__ xb,     // [N][32] dwords (bf16x2)
    const float* __restrict__ A1x,     // [N][64] f32
    const float* __restrict__ A1e,     // [N][32] f32
    const int*   __restrict__ deg,
    const ushort16* __restrict__ Wc1T, // [128][160] bf16
    const float* __restrict__ b1eff,
    const float* __restrict__ bmW1,
    const ushort16* __restrict__ Wm2hT,// [64][128] bf16
    uint32* __restrict__ h1b,          // [N][64] dwords (bf16x2)
    uint32* __restrict__ g2b,          // [N][32] dwords (bf16x2)
    int N)
{
    __shared__ ushort16 sFb[NPB][168];  // 160 used, 336B stride
    __shared__ ushort16 sHb[NPB][168];  // 128 used
    __shared__ float sCnt[NPB];

    int t = threadIdx.x;
    int base = blockIdx.x * NPB;
    int tr = t >> 4, c16 = t & 15;
    int v = base + tr;
    bool vok = v < N;

    uint32* sFrow = (uint32*)&sFb[tr][0];
#pragma unroll
    for (int m = 0; m < 5; m++) {
        int d = c16 + 16 * m;
        uint32 w = 0;
        if (vok) {
            if (d < 32) {
                w = xb[(size_t)v * 32 + d];
            } else if (d < 64) {
                int o = (d - 32) * 2;
                w = pack_bf16x2(A1x[(size_t)v * 64 + o], A1x[(size_t)v * 64 + o + 1]);
            } else {
                int o = (d - 64) * 2;
                w = pack_bf16x2(A1e[(size_t)v * 32 + o], A1e[(size_t)v * 32 + o + 1]);
            }
        }
        sFrow[d] = w;
    }
    if (t < NPB) sCnt[t] = (base + t < N) ? (float)deg[base + t] : 1.f;
    __syncthreads();

    int lane = t & 63;
    int wv = t >> 6;
    int lr = lane & 15;
    int kg = lane >> 4;

    f32x4 acc0 = {0.f, 0.f, 0.f, 0.f};
    f32x4 acc1 = {0.f, 0.f, 0.f, 0.f};
    const ushort16* bp1 = &Wc1T[(size_t)(wv * 16 + lr) * 160 + kg * 8];
#pragma unroll
    for (int kt = 0; kt < 5; kt++) {
        bf16x8 a0 = *(const bf16x8*)&sFb[lr][kt * 32 + kg * 8];
        bf16x8 a1 = *(const bf16x8*)&sFb[16 + lr][kt * 32 + kg * 8];
        bf16x8 b  = *(const bf16x8*)&bp1[kt * 32];
        acc0 = MFMA16(a0, b, acc0);
        acc1 = MFMA16(a1, b, acc1);
    }
    int col = wv * 16 + lr;
    float bj = b1eff[col], bw = bmW1[col];
#pragma unroll
    for (int rt = 0; rt < 2; rt++) {
        f32x4 acc = rt ? acc1 : acc0;
        int r0 = rt * 16 + kg * 4;
#pragma unroll
        for (int reg = 0; reg < 4; reg++) {
            float c = sCnt[r0 + reg];
            float hv = fmaxf(acc[reg] + (c > 0.f ? bj : bj - bw), 0.f);
            float other = __shfl_xor(hv, 1);
            if (!(lane & 1))
                ((uint32*)&sHb[r0 + reg][0])[col >> 1] = pack_bf16x2(hv, other);
        }
    }
    __syncthreads();

#pragma unroll
    for (int m = 0; m < 4; m++) {
        int d = c16 + 16 * m;
        if (vok) h1b[(size_t)v * 64 + d] = ((uint32*)&sHb[tr][0])[d];
    }

    int rt2 = wv >> 2, ct2 = wv & 3;
    f32x4 accg = {0.f, 0.f, 0.f, 0.f};
    const ushort16* bp2 = &Wm2hT[(size_t)(ct2 * 16 + lr) * 128 + kg * 8];
#pragma unroll
    for (int kt = 0; kt < 4; kt++) {
        bf16x8 a = *(const bf16x8*)&sHb[rt2 * 16 + lr][kt * 32 + kg * 8];
        bf16x8 b = *(const bf16x8*)&bp2[kt * 32];
        accg = MFMA16(a, b, accg);
    }
    int colg = ct2 * 16 + lr;
    int rg0 = rt2 * 16 + kg * 4;
#pragma unroll
    for (int reg = 0; reg < 4; reg++) {
        float other = __shfl_xor(accg[reg], 1);
        int vr = base + rg0 + reg;
        if (!(lane & 1) && vr < N)
            g2b[(size_t)vr * 32 + (colg >> 1)] = pack_bf16x2(accg[reg], other);
    }
}

// ---------------------------------------------------------------------------
// Layer-2 node kernel (MFMA) — unchanged
// ---------------------------------------------------------------------------
__global__ __launch_bounds__(512) void node2_kernel(
    const uint32* __restrict__ h1b,    // [N][64] dwords
    const float* __restrict__ A2g,     // [N][64] f32
    const float* __restrict__ A1e,     // [N][32] f32
    const int*   __restrict__ deg,
    const ushort16* __restrict__ Wc2T, // [64][224] bf16
    const float* __restrict__ b2eff,
    const float* __restrict__ bmW2,
    float* __restrict__ out,
    int N)
{
    __shared__ ushort16 sFb[NPB][232];  // 224 used, 464B stride
    __shared__ float sCnt[NPB];

    int t = threadIdx.x;
    int base = blockIdx.x * NPB;
    int tr = t >> 4, c16 = t & 15;
    int v = base + tr;
    bool vok = v < N;

    uint32* sFrow = (uint32*)&sFb[tr][0];
#pragma unroll
    for (int m = 0; m < 7; m++) {
        int d = c16 + 16 * m;
        uint32 w = 0;
        if (vok) {
            if (d < 64) {
                w = h1b[(size_t)v * 64 + d];
            } else if (d < 96) {
                int o = (d - 64) * 2;
                w = pack_bf16x2(A2g[(size_t)v * 64 + o], A2g[(size_t)v * 64 + o + 1]);
            } else {
                int o = (d - 96) * 2;
                w = pack_bf16x2(A1e[(size_t)v * 32 + o], A1e[(size_t)v * 32 + o + 1]);
            }
        }
        sFrow[d] = w;
    }
    if (t < NPB) sCnt[t] = (base + t < N) ? (float)deg[base + t] : 1.f;
    __syncthreads();

    int lane = t & 63;
    int wv = t >> 6;
    int lr = lane & 15;
    int kg = lane >> 4;
    int rt = wv >> 2, ct = wv & 3;

    f32x4 acc = {0.f, 0.f, 0.f, 0.f};
    const ushort16* bp = &Wc2T[(size_t)(ct * 16 + lr) * 224 + kg * 8];
#pragma unroll
    for (int kt = 0; kt < 7; kt++) {
        bf16x8 a = *(const bf16x8*)&sFb[rt * 16 + lr][kt * 32 + kg * 8];
        bf16x8 b = *(const bf16x8*)&bp[kt * 32];
        acc = MFMA16(a, b, acc);
    }
    int col = ct * 16 + lr;
    float bj = b2eff[col], bw = bmW2[col];
    int r0 = rt * 16 + kg * 4;
#pragma unroll
    for (int reg = 0; reg < 4; reg++) {
        int vr = base + r0 + reg;
        float c = sCnt[r0 + reg];
        float bias = (c > 0.f) ? bj : bj - bw;
        if (vr < N) out[(size_t)vr * 64 + col] = fmaxf(acc[reg] + bias, 0.f);
    }
}

// ---------------------------------------------------------------------------
extern "C" void kernel_launch(void* const* d_in, const int* in_sizes, int n_in,
                              void* d_out, int out_size, void* d_ws, size_t ws_size,
                              hipStream_t stream) {
    const float* x      = (const float*)d_in[0];
    const int*   ei     = (const int*)d_in[1];
    const float* ea     = (const float*)d_in[2];
    const float* Wmsg1  = (const float*)d_in[3];
    const float* bmsg1  = (const float*)d_in[4];
    const float* Wapp1  = (const float*)d_in[5];
    const float* bapp1  = (const float*)d_in[6];
    const float* Wmsg2  = (const float*)d_in[7];
    const float* bmsg2  = (const float*)d_in[8];
    const float* Wapp2  = (const float*)d_in[9];
    const float* bapp2  = (const float*)d_in[10];

    const int N = in_sizes[0] / 64;      // 50000
    const int E = in_sizes[1] / 2;       // 800000
    const int NCH = (N + SCAN_CHUNK - 1) / SCAN_CHUNK;
    const int* src = ei;
    const int* dst = ei + E;

    uint8_t* p = (uint8_t*)d_ws;
    auto alloc = [&](size_t bytes) -> void* {
        void* r = (void*)p;
        p += (bytes + 255) & ~(size_t)255;
        return r;
    };
    int*     deg    = (int*)alloc((size_t)(N + 3) / 4 * 16);  // int4-aligned
    int*     off    = (int*)alloc((size_t)(N + 1) * 4);
    int*     cursor = (int*)alloc((size_t)N * 4);
    int*     part   = (int*)alloc((size_t)NCH * 4);
    int2*    elist  = (int2*)alloc((size_t)E * 8);
    float*   A1x    = (float*)alloc((size_t)N * 64 * 4);  // reused as A2g
    float*   A1e    = (float*)alloc((size_t)N * 32 * 4);
    uint32*  xb     = (uint32*)alloc((size_t)N * 32 * 4);
    uint32*  h1b    = (uint32*)alloc((size_t)N * 64 * 4);
    uint32*  g2b    = (uint32*)alloc((size_t)N * 32 * 4);
    ushort16* Wc1T  = (ushort16*)alloc(128 * 160 * 2);
    ushort16* Wc2T  = (ushort16*)alloc(64 * 224 * 2);
    ushort16* Wm2hT = (ushort16*)alloc(64 * 128 * 2);
    float*   b1eff  = (float*)alloc(128 * 4);
    float*   bmW1   = (float*)alloc(128 * 4);
    float*   b2eff  = (float*)alloc(64 * 4);
    float*   bmW2   = (float*)alloc(64 * 4);
    float*   A2g    = A1x;   // safe: A1x consumed by node1 before agg2 writes A2g

    // Zero deg with our own kernel (runtime fillBuffer for small sizes is ~60us!)
    {
        int n4 = (N + 3) / 4;
        zero_kernel<<<(n4 + 255) / 256, 256, 0, stream>>>((int4*)deg, n4);
    }

    // Weight composition + x conversion
    compose1_kernel<<<161, 128, 0, stream>>>(Wmsg1, bmsg1, Wapp1, bapp1,
                                             Wc1T, b1eff, bmW1);
    compose2_kernel<<<225, 64, 0, stream>>>(Wmsg2, bmsg2, Wapp2, bapp2,
                                            Wc2T, b2eff, bmW2);
    composem_kernel<<<128, 64, 0, stream>>>(Wmsg2, Wm2hT);
    {
        int n4 = N * 16;
        cvt_x_kernel<<<(n4 + 255) / 256, 256, 0, stream>>>(
            (const float4*)x, (uint2*)xb, n4);
    }

    // CSR build (8 edges/thread)
    {
        int ngroups = (E + 7) / 8;
        hist_kernel<<<(ngroups + 255) / 256, 256, 0, stream>>>(dst, deg, E);
        scanA_kernel<<<NCH, 256, 0, stream>>>(deg, part, N);
        scanB_kernel<<<1, 64, 0, stream>>>(part, off + N, NCH);
        scanC_kernel<<<NCH, SCAN_CHUNK, 0, stream>>>(deg, part, off, cursor, N);
        fill_kernel<<<(ngroups + 255) / 256, 256, 0, stream>>>(src, dst, cursor, elist, E);
    }

    // Layer 1: 8 lanes/node -> 32 nodes per 256-thread block
    agg1_kernel<<<(N + 31) / 32, 256, 0, stream>>>(
        (const uint4*)xb, (const float4*)ea, elist, off,
        (float4*)A1x, (float4*)A1e, N);
    node1_kernel<<<(N + NPB - 1) / NPB, 512, 0, stream>>>(
        xb, A1x, A1e, deg, Wc1T, b1eff, bmW1, Wm2hT, h1b, g2b, N);

    // Layer 2
    agg2_kernel<<<(N + 31) / 32, 256, 0, stream>>>(
        (const uint4*)g2b, elist, off, (float4*)A2g, N);
    node2_kernel<<<(N + NPB - 1) / NPB, 512, 0, stream>>>(
        h1b, A2g, A1e, deg, Wc2T, b2eff, bmW2,
        (float*)d_out, N);
}